// Round 10
// baseline (1258.601 us; speedup 1.0000x reference)
//
#include <hip/hip_runtime.h>
#include <math.h>

#define NF 128      // hidden dim H
#define FIN 256     // in features

typedef unsigned short u16;
typedef unsigned int   u32;
typedef __bf16 bf16x8 __attribute__((ext_vector_type(8)));
typedef float  f32x4  __attribute__((ext_vector_type(4)));

union ABu { uint4 u; bf16x8 v; u16 s[8]; };

__device__ __forceinline__ float bf2f(u16 u) {
    union { u32 i; float f; } v; v.i = ((u32)u) << 16; return v.f;
}
__device__ __forceinline__ u16 f2bf(float f) {
    union { float f; u32 i; } v; v.f = f;
    u32 r = (v.i + 0x7fffu + ((v.i >> 16) & 1u)) >> 16;
    return (u16)r;
}

// ---------------- CSR construction ----------------

__global__ void k_deg(const int* __restrict__ row, int* __restrict__ cnt, int E) {
    int e = blockIdx.x * 256 + threadIdx.x;
    if (e < E) atomicAdd(&cnt[row[e]], 1);
}

__global__ __launch_bounds__(1024) void k_scan1(const int* __restrict__ cnt,
                                                int* __restrict__ incl,
                                                int* __restrict__ part, int n) {
    __shared__ int sm[1024];
    const int t = threadIdx.x;
    const int base = blockIdx.x * 1024;
    int v = (base + t < n) ? cnt[base + t] : 0;
    sm[t] = v;
    __syncthreads();
    for (int off = 1; off < 1024; off <<= 1) {
        int u = (t >= off) ? sm[t - off] : 0;
        __syncthreads();
        sm[t] += u;
        __syncthreads();
    }
    if (base + t < n) incl[base + t] = sm[t];
    if (t == 1023) part[blockIdx.x] = sm[1023];
}

__global__ void k_scan2(int* part, int np) {   // in-place exclusive scan, np <= 128
    __shared__ int sm[128];
    const int t = threadIdx.x;
    int v = (t < np) ? part[t] : 0;
    sm[t] = v;
    __syncthreads();
    for (int off = 1; off < 128; off <<= 1) {
        int u = (t >= off) ? sm[t - off] : 0;
        __syncthreads();
        sm[t] += u;
        __syncthreads();
    }
    if (t < np) part[t] = sm[t] - v;
}

// dnode = {dinv = deg^-1/2, sdeg = deg^+1/2}
__global__ void k_rowptr(const int* __restrict__ cnt, const int* __restrict__ incl,
                         const int* __restrict__ part, int* __restrict__ rowp,
                         int* __restrict__ curs, float2* __restrict__ dnode, int n) {
    int i = blockIdx.x * 256 + threadIdx.x;
    if (i >= n) return;
    int start = incl[i] - cnt[i] + part[i >> 10];
    rowp[i] = start;
    curs[i] = start;
    float deg = (float)cnt[i] + 1.0f;
    dnode[i] = make_float2(rsqrtf(deg), sqrtf(deg));
}

// XCD-pinned bucketed fill: bucket = blockIdx % 8 == (assumed) XCD id.
// All writes to bucket b's contiguous CSR window come from one XCD -> each
// 64B line is dirtied in exactly one L2, evicted once. Blocks with the same
// bucket id grid-stride-partition the edge list among themselves.
__global__ __launch_bounds__(256) void k_fill(const int* __restrict__ row,
                                              const int* __restrict__ col,
                                              int* __restrict__ curs,
                                              int* __restrict__ ccol,
                                              int E, int n) {
    const int bucket = blockIdx.x & 7;
    const int bw = (n + 7) >> 3;
    const int lo = bucket * bw;
    const int hi = min(n, lo + bw);
    const int nb = gridDim.x >> 3;            // blocks per bucket
    const int bi = blockIdx.x >> 3;
    const int stride = nb * 256;
    for (int e = bi * 256 + threadIdx.x; e < E; e += stride) {
        int r = row[e];
        if (r >= lo && r < hi) {
            int p = atomicAdd(&curs[r], 1);
            ccol[p] = col[e];
        }
    }
}

// ---------------- weight prep: fragment-linear bf16 B tables ----------------
// layout elem idx = ((s*8 + j)*64 + lane)*8 + e  ->  B[k = s*32 + (lane>>4)*8 + e][n = j*16 + (lane&15)]

__global__ void k_prepB0(const float* __restrict__ fcw, u16* __restrict__ dst) {
    int idx = blockIdx.x * 256 + threadIdx.x;          // 32768 total (K=256)
    int e = idx & 7, l = (idx >> 3) & 63, j = (idx >> 9) & 7, s = idx >> 12;
    int k = s * 32 + (l >> 4) * 8 + e, n = j * 16 + (l & 15);
    dst[idx] = f2bf(fcw[k * NF + n]);
}

// W'_l = theta_l * W_l + (1-theta_l) * I
__global__ void k_prepBl(const float* __restrict__ Ws, u16* __restrict__ dst, float4 th) {
    int idx = blockIdx.x * 256 + threadIdx.x;          // 4 * 16384 total (K=128)
    int e = idx & 7, l = (idx >> 3) & 63, j = (idx >> 9) & 7, s = (idx >> 12) & 3, ly = idx >> 14;
    int k = s * 32 + (l >> 4) * 8 + e, n = j * 16 + (l & 15);
    float t = (ly == 0) ? th.x : (ly == 1) ? th.y : (ly == 2) ? th.z : th.w;
    float w = t * Ws[(size_t)ly * NF * NF + k * NF + n] + ((k == n) ? (1.f - t) : 0.f);
    dst[idx] = f2bf(w);
}

// ---------------- fused layer: SpMM (gather+add) -> LDS -> MFMA GEMM ----------------
// tblp[c] = bf16(dinv_c * h[c])
// S = 0.9*dinv_r*(sum_e tblp[col_e] + tblp[r]) + 0.1*sdeg_r*tbl0p[r]   (bf16, staged in LDS)
// MODE 1: Cb = bf16(dinv_row * relu(S @ W'))      (next layer's gather table)
// MODE 2: Cf = S @ W'                              (final fp32 output; residual folded in W')
// Block 256 = 4 waves, 64 nodes. Wave w: phase A computes rows w*16..w*16+15 (64 lanes x 2 feats,
// 8-wide MLP gather unroll); phase B MFMA with A-frags from LDS, B-frags from global (L1-resident).

template<int MODE>
__global__ __launch_bounds__(256) void k_layer(const u16* __restrict__ tblp,
                                               const u16* __restrict__ tbl0p,
                                               const int* __restrict__ rowp,
                                               const int* __restrict__ endp,
                                               const int* __restrict__ ccol,
                                               const float2* __restrict__ dnode,
                                               const uint4* __restrict__ Bfrag,
                                               u16* __restrict__ Cb,
                                               float* __restrict__ Cf, int n) {
    __shared__ u16 Ss[64][136];               // +8 pad: 272B row stride, 16B aligned
    const int lane = threadIdx.x & 63, wave = threadIdx.x >> 6;
    const int nb = blockIdx.x * 64;
    const int f2 = lane << 1;

    #pragma unroll 1
    for (int i = 0; i < 16; i++) {
        const int node = nb + wave * 16 + i;
        u32 outw = 0;
        if (node < n) {
            const size_t rb = (size_t)node * NF + f2;
            u32 us = *(const u32*)(tblp + rb);             // self term (pre-scaled)
            float ax = bf2f((u16)us), ay = bf2f((u16)(us >> 16));
            int p = rowp[node];
            const int e = endp[node];
            while (p + 8 <= e) {
                int c[8];
                #pragma unroll
                for (int q = 0; q < 8; q++) c[q] = ccol[p + q];
                u32 u[8];
                #pragma unroll
                for (int q = 0; q < 8; q++)
                    u[q] = *(const u32*)(tblp + (size_t)c[q] * NF + f2);
                #pragma unroll
                for (int q = 0; q < 8; q++) {
                    ax += bf2f((u16)u[q]);
                    ay += bf2f((u16)(u[q] >> 16));
                }
                p += 8;
            }
            while (p < e) {
                int c = ccol[p++];
                u32 u = *(const u32*)(tblp + (size_t)c * NF + f2);
                ax += bf2f((u16)u);
                ay += bf2f((u16)(u >> 16));
            }
            const float2 dn = dnode[node];
            u32 h0u = *(const u32*)(tbl0p + rb);
            float ox = 0.9f * dn.x * ax + 0.1f * dn.y * bf2f((u16)h0u);
            float oy = 0.9f * dn.x * ay + 0.1f * dn.y * bf2f((u16)(h0u >> 16));
            outw = (u32)f2bf(ox) | ((u32)f2bf(oy) << 16);
        }
        *(u32*)&Ss[wave * 16 + i][f2] = outw;
    }
    __syncthreads();

    const int m = lane & 15, kg = lane >> 4;
    ABu af[4];
    #pragma unroll
    for (int s = 0; s < 4; s++)
        af[s].u = *(const uint4*)&Ss[wave * 16 + m][s * 32 + kg * 8];

    f32x4 acc[8];
    #pragma unroll
    for (int j = 0; j < 8; j++) acc[j] = (f32x4){0.f, 0.f, 0.f, 0.f};
    #pragma unroll
    for (int s = 0; s < 4; s++) {
        #pragma unroll
        for (int j = 0; j < 8; j++) {
            ABu b;
            b.u = Bfrag[(s * 8 + j) * 64 + lane];
            acc[j] = __builtin_amdgcn_mfma_f32_16x16x32_bf16(af[s].v, b.v, acc[j], 0, 0, 0);
        }
    }

    // C/D layout: col = j*16 + (lane&15), row = base + (lane>>4)*4 + reg  [m89-verified]
    const int orow0 = nb + wave * 16 + kg * 4;
    #pragma unroll
    for (int r = 0; r < 4; r++) {
        const int orow = orow0 + r;
        if (orow >= n) continue;
        if (MODE == 2) {
            #pragma unroll
            for (int j = 0; j < 8; j++)
                Cf[(size_t)orow * NF + j * 16 + m] = acc[j][r];
        } else {
            const float dv = dnode[orow].x;
            #pragma unroll
            for (int j = 0; j < 8; j++)
                Cb[(size_t)orow * NF + j * 16 + m] = f2bf(dv * fmaxf(acc[j][r], 0.f));
        }
    }
}

// ---------------- MFMA bf16 GEMM for h0: Cb = bf16(dinv*(x @ fc_w + bias)) ----------------
// A fp32 [N,256]; B pre-packed fragment-linear in LDS; 4 waves, 64 rows/block.

__global__ __launch_bounds__(256) void k_gemm0(const float* __restrict__ A,
                                               const uint4* __restrict__ Bfrag,
                                               const float* __restrict__ bias,
                                               const float2* __restrict__ dnode,
                                               u16* __restrict__ Cb,
                                               int nrows) {
    constexpr int K = FIN, KS = K / 32;
    __shared__ u16 Bs[K * NF];
    const int tid = threadIdx.x;
    uint4* Bs4 = (uint4*)Bs;
    for (int i = tid; i < K * NF / 8; i += 256) Bs4[i] = Bfrag[i];
    __syncthreads();

    const int lane = tid & 63, wave = tid >> 6;
    const int m = lane & 15, kg = lane >> 4;
    const int row = blockIdx.x * 64 + wave * 16 + m;
    const bool rok = row < nrows;

    ABu af[KS];
    #pragma unroll
    for (int s = 0; s < KS; s++) {
        float4 f0 = {0.f, 0.f, 0.f, 0.f}, f1 = {0.f, 0.f, 0.f, 0.f};
        if (rok) {
            f0 = *(const float4*)(A + (size_t)row * K + s * 32 + kg * 8);
            f1 = *(const float4*)(A + (size_t)row * K + s * 32 + kg * 8 + 4);
        }
        af[s].s[0] = f2bf(f0.x); af[s].s[1] = f2bf(f0.y);
        af[s].s[2] = f2bf(f0.z); af[s].s[3] = f2bf(f0.w);
        af[s].s[4] = f2bf(f1.x); af[s].s[5] = f2bf(f1.y);
        af[s].s[6] = f2bf(f1.z); af[s].s[7] = f2bf(f1.w);
    }

    f32x4 acc[8];
    #pragma unroll
    for (int j = 0; j < 8; j++) acc[j] = (f32x4){0.f, 0.f, 0.f, 0.f};
    #pragma unroll
    for (int s = 0; s < KS; s++) {
        #pragma unroll
        for (int j = 0; j < 8; j++) {
            ABu b;
            b.u = *((const uint4*)Bs + (s * 8 + j) * 64 + lane);
            acc[j] = __builtin_amdgcn_mfma_f32_16x16x32_bf16(af[s].v, b.v, acc[j], 0, 0, 0);
        }
    }

    const int orow0 = blockIdx.x * 64 + wave * 16 + kg * 4;
    #pragma unroll
    for (int r = 0; r < 4; r++) {
        const int orow = orow0 + r;
        if (orow >= nrows) continue;
        const float dv = dnode[orow].x;
        #pragma unroll
        for (int j = 0; j < 8; j++)
            Cb[(size_t)orow * NF + j * 16 + m] = f2bf(dv * (acc[j][r] + bias[j * 16 + m]));
    }
}

// ---------------- host launch ----------------

extern "C" void kernel_launch(void* const* d_in, const int* in_sizes, int n_in,
                              void* d_out, int out_size, void* d_ws, size_t ws_size,
                              hipStream_t stream) {
    const float* x   = (const float*)d_in[0];
    const float* fcw = (const float*)d_in[1];
    const float* fcb = (const float*)d_in[2];
    const float* Ws  = (const float*)d_in[3];
    const int*   ei  = (const int*)d_in[4];
    const int N = in_sizes[0] / FIN;
    const int E = in_sizes[4] / 2;
    const int* row = ei;
    const int* col = ei + E;
    float* out = (float*)d_out;

    char* base = (char*)d_ws;
    size_t off = 0;
    auto alloc = [&](size_t b) -> char* {
        char* p = base + off;
        off += (b + 255) & ~(size_t)255;
        return p;
    };
    u16*    tbl0p = (u16*)alloc((size_t)N * NF * sizeof(u16));    // bf16(dinv * h0)
    u16*    hb    = (u16*)alloc((size_t)N * NF * sizeof(u16));    // bf16(dinv * h_l)
    int*    ccol  = (int*)alloc((size_t)E * sizeof(int));
    u16*    Bf0   = (u16*)alloc(32768 * sizeof(u16));             // fc_w frag table
    u16*    Bfl   = (u16*)alloc(65536 * sizeof(u16));             // 4x W' frag tables
    int*    cnt   = (int*)alloc((size_t)N * sizeof(int));
    int*    incl  = (int*)alloc((size_t)N * sizeof(int));
    int*    rowp  = (int*)alloc((size_t)N * sizeof(int));
    int*    curs  = (int*)alloc((size_t)N * sizeof(int));
    float2* dnode = (float2*)alloc((size_t)N * sizeof(float2));
    int*    part  = (int*)alloc(1024);
    if (off > ws_size) return;   // ws too small: fail loudly (no corruption)

    hipMemsetAsync(cnt, 0, (size_t)N * sizeof(int), stream);
    const int eb = (E + 255) / 256;
    k_deg<<<eb, 256, 0, stream>>>(row, cnt, E);
    const int nch = (N + 1023) / 1024;
    k_scan1<<<nch, 1024, 0, stream>>>(cnt, incl, part, N);
    k_scan2<<<1, 128, 0, stream>>>(part, nch);
    k_rowptr<<<(N + 255) / 256, 256, 0, stream>>>(cnt, incl, part, rowp, curs, dnode, N);
    k_fill<<<2048, 256, 0, stream>>>(row, col, curs, ccol, E, N);

    const float4 th4 = make_float4(logf(1.5f), logf(1.25f), logf(7.f / 6.f), logf(1.125f));
    k_prepB0<<<128, 256, 0, stream>>>(fcw, Bf0);
    k_prepBl<<<256, 256, 0, stream>>>(Ws, Bfl, th4);

    const int gb = (N + 63) / 64;
    // tbl0p = bf16(dinv * (x @ fc_w + fc_b))
    k_gemm0<<<gb, 256, 0, stream>>>(x, (const uint4*)Bf0, fcb, dnode, tbl0p, N);

    const u16* tbl = tbl0p;
    for (int l = 1; l <= 4; l++) {
        const uint4* Bf = (const uint4*)(Bfl + (size_t)(l - 1) * 16384);
        if (l < 4) {
            k_layer<1><<<gb, 256, 0, stream>>>(tbl, tbl0p, rowp, curs, ccol, dnode, Bf, hb, nullptr, N);
            tbl = hb;
        } else {
            k_layer<2><<<gb, 256, 0, stream>>>(tbl, tbl0p, rowp, curs, ccol, dnode, Bf, nullptr, out, N);
        }
    }
}

// Round 16
// 993.134 us; speedup vs baseline: 1.2673x; 1.2673x over previous
//
#include <hip/hip_runtime.h>
#include <math.h>

#define NF 128      // hidden dim H
#define FIN 256     // in features

typedef unsigned short u16;
typedef unsigned int   u32;
typedef __bf16 bf16x8 __attribute__((ext_vector_type(8)));
typedef float  f32x4  __attribute__((ext_vector_type(4)));

union ABu { uint4 u; bf16x8 v; u16 s[8]; };

__device__ __forceinline__ float bf2f(u16 u) {
    union { u32 i; float f; } v; v.i = ((u32)u) << 16; return v.f;
}
__device__ __forceinline__ u16 f2bf(float f) {
    union { float f; u32 i; } v; v.f = f;
    u32 r = (v.i + 0x7fffu + ((v.i >> 16) & 1u)) >> 16;
    return (u16)r;
}

// ---------------- CSR construction ----------------

__global__ void k_deg(const int* __restrict__ row, int* __restrict__ cnt, int E) {
    int e = blockIdx.x * 256 + threadIdx.x;
    if (e < E) atomicAdd(&cnt[row[e]], 1);
}

__global__ __launch_bounds__(1024) void k_scan1(const int* __restrict__ cnt,
                                                int* __restrict__ incl,
                                                int* __restrict__ part, int n) {
    __shared__ int sm[1024];
    const int t = threadIdx.x;
    const int base = blockIdx.x * 1024;
    int v = (base + t < n) ? cnt[base + t] : 0;
    sm[t] = v;
    __syncthreads();
    for (int off = 1; off < 1024; off <<= 1) {
        int u = (t >= off) ? sm[t - off] : 0;
        __syncthreads();
        sm[t] += u;
        __syncthreads();
    }
    if (base + t < n) incl[base + t] = sm[t];
    if (t == 1023) part[blockIdx.x] = sm[1023];
}

__global__ void k_scan2(int* part, int np) {   // in-place exclusive scan, np <= 128
    __shared__ int sm[128];
    const int t = threadIdx.x;
    int v = (t < np) ? part[t] : 0;
    sm[t] = v;
    __syncthreads();
    for (int off = 1; off < 128; off <<= 1) {
        int u = (t >= off) ? sm[t - off] : 0;
        __syncthreads();
        sm[t] += u;
        __syncthreads();
    }
    if (t < np) part[t] = sm[t] - v;
}

// dnode = {dinv = deg^-1/2, sdeg = deg^+1/2}
__global__ void k_rowptr(const int* __restrict__ cnt, const int* __restrict__ incl,
                         const int* __restrict__ part, int* __restrict__ rowp,
                         int* __restrict__ curs, float2* __restrict__ dnode, int n) {
    int i = blockIdx.x * 256 + threadIdx.x;
    if (i >= n) return;
    int start = incl[i] - cnt[i] + part[i >> 10];
    rowp[i] = start;
    curs[i] = start;
    float deg = (float)cnt[i] + 1.0f;
    dnode[i] = make_float2(rsqrtf(deg), sqrtf(deg));
}

// XCD-pinned bucketed fill (validated R10: left top-5, was 280us in R6).
// bucket = blockIdx % 8 == XCD id; each bucket's CSR window is written from one XCD.
__global__ __launch_bounds__(256) void k_fill(const int* __restrict__ row,
                                              const int* __restrict__ col,
                                              int* __restrict__ curs,
                                              int* __restrict__ ccol,
                                              int E, int n) {
    const int bucket = blockIdx.x & 7;
    const int bw = (n + 7) >> 3;
    const int lo = bucket * bw;
    const int hi = min(n, lo + bw);
    const int nb = gridDim.x >> 3;            // blocks per bucket
    const int bi = blockIdx.x >> 3;
    const int stride = nb * 256;
    for (int e = bi * 256 + threadIdx.x; e < E; e += stride) {
        int r = row[e];
        if (r >= lo && r < hi) {
            int p = atomicAdd(&curs[r], 1);
            ccol[p] = col[e];
        }
    }
}

// ---------------- weight prep: fragment-linear bf16 B tables ----------------
// layout elem idx = ((s*8 + j)*64 + lane)*8 + e  ->  B[k = s*32 + (lane>>4)*8 + e][n = j*16 + (lane&15)]

__global__ void k_prepB0(const float* __restrict__ fcw, u16* __restrict__ dst) {
    int idx = blockIdx.x * 256 + threadIdx.x;          // 32768 total (K=256)
    int e = idx & 7, l = (idx >> 3) & 63, j = (idx >> 9) & 7, s = idx >> 12;
    int k = s * 32 + (l >> 4) * 8 + e, n = j * 16 + (l & 15);
    dst[idx] = f2bf(fcw[k * NF + n]);
}

// W'_l = theta_l * W_l + (1-theta_l) * I
__global__ void k_prepBl(const float* __restrict__ Ws, u16* __restrict__ dst, float4 th) {
    int idx = blockIdx.x * 256 + threadIdx.x;          // 4 * 16384 total (K=128)
    int e = idx & 7, l = (idx >> 3) & 63, j = (idx >> 9) & 7, s = (idx >> 12) & 3, ly = idx >> 14;
    int k = s * 32 + (l >> 4) * 8 + e, n = j * 16 + (l & 15);
    float t = (ly == 0) ? th.x : (ly == 1) ? th.y : (ly == 2) ? th.z : th.w;
    float w = t * Ws[(size_t)ly * NF * NF + k * NF + n] + ((k == n) ? (1.f - t) : 0.f);
    dst[idx] = f2bf(w);
}

// ---------------- SpMM: pure gather+add on pre-scaled bf16 table ----------------
// UNFUSED on purpose (R10 lesson): 4 nodes/block, grid ~25000 -> ~87% occupancy.
// The gather is latency-bound; wave count is the scarce resource. S round-trip
// (51MB/layer) streams at full BW and is cheap by comparison.
// tblp[c] = bf16(dinv_c * h[c]);  Sb = bf16(0.9*dinv_r*(sum_e tblp[col_e] + tblp[r])
//                                           + 0.1*sdeg_r*tbl0p[r])

__global__ __launch_bounds__(256) void k_spmm(const u16* __restrict__ tblp,
                                              const u16* __restrict__ tbl0p,
                                              const int* __restrict__ rowp,
                                              const int* __restrict__ endp,
                                              const int* __restrict__ ccol,
                                              const float2* __restrict__ dnode,
                                              u16* __restrict__ Sb, int n) {
    const int node = blockIdx.x * 4 + (threadIdx.x >> 6);
    if (node >= n) return;
    const int f2 = (threadIdx.x & 63) << 1;
    const size_t rb = (size_t)node * NF + f2;

    u32 us = *(const u32*)(tblp + rb);                 // self term (pre-scaled)
    float ax = bf2f((u16)us), ay = bf2f((u16)(us >> 16));

    int p = rowp[node];
    const int e = endp[node];
    while (p + 8 <= e) {
        int c[8];
        #pragma unroll
        for (int i = 0; i < 8; i++) c[i] = ccol[p + i];
        u32 u[8];
        #pragma unroll
        for (int i = 0; i < 8; i++)
            u[i] = *(const u32*)(tblp + (size_t)c[i] * NF + f2);
        #pragma unroll
        for (int i = 0; i < 8; i++) {
            ax += bf2f((u16)u[i]);
            ay += bf2f((u16)(u[i] >> 16));
        }
        p += 8;
    }
    while (p < e) {
        int c = ccol[p++];
        u32 u = *(const u32*)(tblp + (size_t)c * NF + f2);
        ax += bf2f((u16)u);
        ay += bf2f((u16)(u >> 16));
    }

    const float2 dn = dnode[node];
    u32 h0u = *(const u32*)(tbl0p + rb);
    float ox = 0.9f * dn.x * ax + 0.1f * dn.y * bf2f((u16)h0u);
    float oy = 0.9f * dn.x * ay + 0.1f * dn.y * bf2f((u16)(h0u >> 16));
    *(u32*)(Sb + rb) = (u32)f2bf(ox) | ((u32)f2bf(oy) << 16);
}

// ---------------- MFMA bf16 GEMM: C[N,128] = A[N,K] @ B'[K,128] ----------------
// MODE 0: A fp32; Cb = bf16(dinv_row * (acc + bias))        (writes scaled h0 table)
// MODE 1: A bf16; Cb = bf16(dinv_row * relu(acc))           (writes scaled h table)
// MODE 2: A bf16; Cf = acc (fp32, final output; residual folded in W')
// Block 256 = 4 waves; 64 rows/block. B pre-packed fragment-linear in LDS;
// A-frags loaded direct from global (no barriers in K-loop).

template<int K, int MODE>
__global__ __launch_bounds__(256) void k_gemmM(const void* __restrict__ Ap,
                                               const uint4* __restrict__ Bfrag,
                                               const float* __restrict__ bias,
                                               const float2* __restrict__ dnode,
                                               u16* __restrict__ Cb,
                                               float* __restrict__ Cf,
                                               int nrows) {
    constexpr int KS = K / 32;
    __shared__ u16 Bs[K * NF];
    const int tid = threadIdx.x;
    constexpr int NV = K * NF / 8;           // uint4 count
    uint4* Bs4 = (uint4*)Bs;
    for (int i = tid; i < NV; i += 256) Bs4[i] = Bfrag[i];
    __syncthreads();

    const int lane = tid & 63, wave = tid >> 6;
    const int m = lane & 15, kg = lane >> 4;
    const int row = blockIdx.x * 64 + wave * 16 + m;
    const bool rok = row < nrows;

    ABu af[KS];
    if (MODE == 0) {
        const float* A = (const float*)Ap;
        #pragma unroll
        for (int s = 0; s < KS; s++) {
            float4 f0 = {0.f, 0.f, 0.f, 0.f}, f1 = {0.f, 0.f, 0.f, 0.f};
            if (rok) {
                f0 = *(const float4*)(A + (size_t)row * K + s * 32 + kg * 8);
                f1 = *(const float4*)(A + (size_t)row * K + s * 32 + kg * 8 + 4);
            }
            af[s].s[0] = f2bf(f0.x); af[s].s[1] = f2bf(f0.y);
            af[s].s[2] = f2bf(f0.z); af[s].s[3] = f2bf(f0.w);
            af[s].s[4] = f2bf(f1.x); af[s].s[5] = f2bf(f1.y);
            af[s].s[6] = f2bf(f1.z); af[s].s[7] = f2bf(f1.w);
        }
    } else {
        const u16* A = (const u16*)Ap;
        #pragma unroll
        for (int s = 0; s < KS; s++) {
            if (rok) af[s].u = *(const uint4*)(A + (size_t)row * K + s * 32 + kg * 8);
            else     af[s].u = make_uint4(0, 0, 0, 0);
        }
    }

    f32x4 acc[8];
    #pragma unroll
    for (int j = 0; j < 8; j++) acc[j] = (f32x4){0.f, 0.f, 0.f, 0.f};

    #pragma unroll
    for (int s = 0; s < KS; s++) {
        #pragma unroll
        for (int j = 0; j < 8; j++) {
            ABu b;
            b.u = *((const uint4*)Bs + (s * 8 + j) * 64 + lane);
            acc[j] = __builtin_amdgcn_mfma_f32_16x16x32_bf16(af[s].v, b.v, acc[j], 0, 0, 0);
        }
    }

    // C/D layout: col = j*16 + (lane&15), row = base + (lane>>4)*4 + reg  [m89-verified]
    const int orow0 = blockIdx.x * 64 + wave * 16 + kg * 4;
    #pragma unroll
    for (int r = 0; r < 4; r++) {
        const int orow = orow0 + r;
        if (orow >= nrows) continue;
        if (MODE == 2) {
            #pragma unroll
            for (int j = 0; j < 8; j++)
                Cf[(size_t)orow * NF + j * 16 + m] = acc[j][r];
        } else {
            const float dv = dnode[orow].x;
            #pragma unroll
            for (int j = 0; j < 8; j++) {
                float v = acc[j][r];
                if (MODE == 0) v += bias[j * 16 + m];
                else           v = fmaxf(v, 0.f);
                Cb[(size_t)orow * NF + j * 16 + m] = f2bf(dv * v);
            }
        }
    }
}

// ---------------- host launch ----------------

extern "C" void kernel_launch(void* const* d_in, const int* in_sizes, int n_in,
                              void* d_out, int out_size, void* d_ws, size_t ws_size,
                              hipStream_t stream) {
    const float* x   = (const float*)d_in[0];
    const float* fcw = (const float*)d_in[1];
    const float* fcb = (const float*)d_in[2];
    const float* Ws  = (const float*)d_in[3];
    const int*   ei  = (const int*)d_in[4];
    const int N = in_sizes[0] / FIN;
    const int E = in_sizes[4] / 2;
    const int* row = ei;
    const int* col = ei + E;
    float* out = (float*)d_out;

    char* base = (char*)d_ws;
    size_t off = 0;
    auto alloc = [&](size_t b) -> char* {
        char* p = base + off;
        off += (b + 255) & ~(size_t)255;
        return p;
    };
    u16*    tbl0p = (u16*)alloc((size_t)N * NF * sizeof(u16));    // bf16(dinv * h0)
    u16*    hb    = (u16*)alloc((size_t)N * NF * sizeof(u16));    // bf16(dinv * h_l)
    u16*    Sb    = (u16*)alloc((size_t)N * NF * sizeof(u16));    // bf16 support (GEMM A)
    int*    ccol  = (int*)alloc((size_t)E * sizeof(int));
    u16*    Bf0   = (u16*)alloc(32768 * sizeof(u16));             // fc_w frag table
    u16*    Bfl   = (u16*)alloc(65536 * sizeof(u16));             // 4x W' frag tables
    int*    cnt   = (int*)alloc((size_t)N * sizeof(int));
    int*    incl  = (int*)alloc((size_t)N * sizeof(int));
    int*    rowp  = (int*)alloc((size_t)N * sizeof(int));
    int*    curs  = (int*)alloc((size_t)N * sizeof(int));
    float2* dnode = (float2*)alloc((size_t)N * sizeof(float2));
    int*    part  = (int*)alloc(1024);
    if (off > ws_size) return;   // ws too small: fail loudly (no corruption)

    hipMemsetAsync(cnt, 0, (size_t)N * sizeof(int), stream);
    const int eb = (E + 255) / 256;
    k_deg<<<eb, 256, 0, stream>>>(row, cnt, E);
    const int nch = (N + 1023) / 1024;
    k_scan1<<<nch, 1024, 0, stream>>>(cnt, incl, part, N);
    k_scan2<<<1, 128, 0, stream>>>(part, nch);
    k_rowptr<<<(N + 255) / 256, 256, 0, stream>>>(cnt, incl, part, rowp, curs, dnode, N);
    k_fill<<<2048, 256, 0, stream>>>(row, col, curs, ccol, E, N);

    const float4 th4 = make_float4(logf(1.5f), logf(1.25f), logf(7.f / 6.f), logf(1.125f));
    k_prepB0<<<128, 256, 0, stream>>>(fcw, Bf0);
    k_prepBl<<<256, 256, 0, stream>>>(Ws, Bfl, th4);

    const int gb = (N + 63) / 64;
    // tbl0p = bf16(dinv * (x @ fc_w + fc_b))
    k_gemmM<FIN, 0><<<gb, 256, 0, stream>>>(x, (const uint4*)Bf0, fcb, dnode, tbl0p, nullptr, N);

    const u16* tbl = tbl0p;
    for (int l = 1; l <= 4; l++) {
        k_spmm<<<(N + 3) / 4, 256, 0, stream>>>(tbl, tbl0p, rowp, curs, ccol, dnode, Sb, N);
        const uint4* Bf = (const uint4*)(Bfl + (size_t)(l - 1) * 16384);
        if (l < 4) {
            k_gemmM<NF, 1><<<gb, 256, 0, stream>>>(Sb, Bf, nullptr, dnode, hb, nullptr, N);
            tbl = hb;
        } else {
            k_gemmM<NF, 2><<<gb, 256, 0, stream>>>(Sb, Bf, nullptr, nullptr, nullptr, out, N);
        }
    }
}